// Round 7
// baseline (76.787 us; speedup 1.0000x reference)
//
#include <hip/hip_runtime.h>

#define NC    15
#define NACC  46          // pos_sig[15], all_sig[15], npos[15], ce
#define BLOCK 256
#define WPB   4
#define WSTRIDE 16        // 64B line per accumulator slot

typedef float f4 __attribute__((ext_vector_type(4)));
typedef int   i4 __attribute__((ext_vector_type(4)));

template<int CTRL>
__device__ __forceinline__ float dppadd(float x) {
    int y = __builtin_amdgcn_update_dpp(0, __float_as_int(x), CTRL, 0xF, 0xF, true);
    return x + __int_as_float(y);
}
template<int CTRL>
__device__ __forceinline__ int dppi(int x) {
    return __builtin_amdgcn_update_dpp(0, x, CTRL, 0xF, 0xF, true);
}
__device__ __forceinline__ float qsum(float x) {   // sum over quad (one row)
    x = dppadd<0xB1>(x);    // quad_perm xor 1
    x = dppadd<0x4E>(x);    // quad_perm xor 2
    return x;
}
__device__ __forceinline__ int qmin(int x) {       // min over quad
    int a = dppi<0xB1>(x); x = (a < x) ? a : x;
    int b = dppi<0x4E>(x); x = (b < x) ? b : x;
    return x;
}

#define LOADX4(dst, ptr) \
    asm volatile("global_load_dwordx4 %0, %1, off" : "=v"(dst) : "v"(ptr))

__global__ __launch_bounds__(BLOCK, 8) void auch_main(
    const float* __restrict__ logits,
    const int* __restrict__ labels,
    float* __restrict__ ws,
    int niter)
{
    __shared__ float s_red[WPB][NACC];

    const int tid  = threadIdx.x;
    const int lane = tid & 63;
    const int wave = tid >> 6;
    const int k    = lane & 3;          // chunk slot within row
    const int rl   = lane >> 2;         // local row 0..15
    const bool k3  = (k == 3);
    const int  cb  = k3 ? 11 : 4 * k;   // first column this lane covers

    const long long gw   = (long long)blockIdx.x * WPB + wave;
    const long long row0 = gw * (16LL * niter) + rl;
    const float* gx = logits + row0 * NC + cb;
    const int*   gl = labels + row0 * NC + cb;

    float accp0=0,accp1=0,accp2=0,accp3=0;     // sigmoid sum over positives
    float acca0=0,acca1=0,acca2=0,acca3=0;     // sigmoid sum over all
    int   np0=0,  np1=0,  np2=0,  np3=0;       // positive counts
    float accce = 0.f;

    auto compute = [&](const f4& x, const i4& l) {
        float e0 = k3 ? 0.f : __expf(x.x);     // k3 slot0 duplicates col 11 -> mask
        float e1 = __expf(x.y);
        float e2 = __expf(x.z);
        float e3 = __expf(x.w);
        float se = qsum(e0 + e1 + e2 + e3);    // row logsumexp denominator

        int lb0 = k3 ? 0 : (l.x & 1);
        int lb1 = l.y & 1, lb2 = l.z & 1, lb3 = l.w & 1;

        float s0 = e0 * __builtin_amdgcn_rcpf(1.f + e0);   // sigmoid = e/(1+e); masked -> 0
        float s1 = e1 * __builtin_amdgcn_rcpf(1.f + e1);
        float s2 = e2 * __builtin_amdgcn_rcpf(1.f + e2);
        float s3 = e3 * __builtin_amdgcn_rcpf(1.f + e3);
        acca0 += s0; acca1 += s1; acca2 += s2; acca3 += s3;
        accp0 += lb0 ? s0 : 0.f;
        accp1 += lb1 ? s1 : 0.f;
        accp2 += lb2 ? s2 : 0.f;
        accp3 += lb3 ? s3 : 0.f;
        np0 += lb0; np1 += lb1; np2 += lb2; np3 += lb3;

        // first positive column in row (argmax of 0/1 labels)
        int col = lb3 ? cb + 3 : 64;
        col = lb2 ? cb + 2 : col;
        col = lb1 ? cb + 1 : col;
        col = lb0 ? cb     : col;
        float xf = lb3 ? x.w : 0.f;
        xf = lb2 ? x.z : xf;
        xf = lb1 ? x.y : xf;
        xf = lb0 ? x.x : xf;
        int mc = qmin(col);
        float sx = (col == mc) ? xf : 0.f;      // unique owner (col ranges disjoint)
        sx = (mc == 64 && k == 0) ? x.x : sx;   // no positive -> argmax = col 0
        sx = qsum(sx);

        accce += __logf(se) - sx;               // per-quad-uniform; dedup at reduce
    };

    // ---- software-pipelined main loop: 2 x dwordx4 in flight across compute ----
    f4 xA, xB; i4 lA, lB;
    LOADX4(xA, gx); LOADX4(lA, gl);
    for (int i = 0; i < niter; i += 2) {
        LOADX4(xB, gx + 240); LOADX4(lB, gl + 240);
        asm volatile("s_waitcnt vmcnt(2)" ::: "memory");   // xA,lA landed; B in flight
        __builtin_amdgcn_sched_barrier(0);
        compute(xA, lA);
        gx += 480; gl += 480;
        if (i + 2 < niter) {
            LOADX4(xA, gx); LOADX4(lA, gl);
            asm volatile("s_waitcnt vmcnt(2)" ::: "memory");
        } else {
            asm volatile("s_waitcnt vmcnt(0)" ::: "memory");
        }
        __builtin_amdgcn_sched_barrier(0);
        compute(xB, lB);
    }

    // ---- reduce across quads: butterfly over strides 4..32 (k stays fixed) ----
    float npf0 = (float)np0, npf1 = (float)np1, npf2 = (float)np2, npf3 = (float)np3;
#pragma unroll
    for (int m = 4; m <= 32; m <<= 1) {
        accp0 += __shfl_xor(accp0, m); accp1 += __shfl_xor(accp1, m);
        accp2 += __shfl_xor(accp2, m); accp3 += __shfl_xor(accp3, m);
        acca0 += __shfl_xor(acca0, m); acca1 += __shfl_xor(acca1, m);
        acca2 += __shfl_xor(acca2, m); acca3 += __shfl_xor(acca3, m);
        npf0  += __shfl_xor(npf0,  m); npf1  += __shfl_xor(npf1,  m);
        npf2  += __shfl_xor(npf2,  m); npf3  += __shfl_xor(npf3,  m);
        accce += __shfl_xor(accce, m);   // sums one representative lane per quad
    }

    if (lane < 4) {                      // lane == k; classes {4k..} or {12,13,14}
        int base = (lane < 3) ? 4 * lane : 11;
        if (lane < 3) {                  // k3 j0 is the masked duplicate -> skip
            s_red[wave][base] = accp0; s_red[wave][15+base] = acca0; s_red[wave][30+base] = npf0;
        }
        s_red[wave][base+1] = accp1; s_red[wave][15+base+1] = acca1; s_red[wave][30+base+1] = npf1;
        s_red[wave][base+2] = accp2; s_red[wave][15+base+2] = acca2; s_red[wave][30+base+2] = npf2;
        s_red[wave][base+3] = accp3; s_red[wave][15+base+3] = acca3; s_red[wave][30+base+3] = npf3;
    }
    if (lane == 0) s_red[wave][45] = accce;
    __syncthreads();

    // one atomicAdd per block per accumulator into 64B-padded slots
    if (tid < NACC)
        atomicAdd(&ws[tid * WSTRIDE],
                  s_red[0][tid] + s_red[1][tid] + s_red[2][tid] + s_red[3][tid]);
}

__global__ __launch_bounds__(64) void auch_finalize(
    const float* __restrict__ ws, float* __restrict__ out, float Bf)
{
    if (threadIdx.x == 0) {
        float sum_term = 0.f, pen14 = 0.f;
#pragma unroll
        for (int c = 0; c < NC; ++c) {
            float sp = ws[c * WSTRIDE];              // sum sigmoid over pos
            float sa = ws[(15 + c) * WSTRIDE];       // sum sigmoid over all
            float np = ws[(30 + c) * WSTRIDE];       // n_pos
            float sn = sa - sp;
            float nn = Bf - np;
            float mp = sp / fmaxf(np, 1.f);
            float mn = sn / fmaxf(nn, 1.f);
            float pen = (np == 0.f) ? (1.f + mn)
                       : ((nn == 0.f) ? (1.f - mp) : (1.f - mp + mn));
            sum_term += pen;
            if (c == NC - 1) pen14 = pen;
        }
        float ce = ws[45 * WSTRIDE] / Bf;
        out[0] = ce + 0.1f * (sum_term / 15.f);
        out[1] = 0.1f * pen14;
    }
}

extern "C" void kernel_launch(void* const* d_in, const int* in_sizes, int n_in,
                              void* d_out, int out_size, void* d_ws, size_t ws_size,
                              hipStream_t stream)
{
    const float* logits = (const float*)d_in[0];
    const int*   labels = (const int*)d_in[1];
    float* ws  = (float*)d_ws;
    float* out = (float*)d_out;

    const long long total = in_sizes[0];      // B*C = 15728640
    const int brows = (int)(total / NC);      // 1048576

    const int grid  = 2048;
    const int niter = brows / (grid * WPB * 16);   // 8 (even -> pipeline i+=2 ok)

    hipMemsetAsync(d_ws, 0, NACC * WSTRIDE * sizeof(float), stream);
    auch_main<<<grid, BLOCK, 0, stream>>>(logits, labels, ws, niter);
    auch_finalize<<<1, 64, 0, stream>>>(ws, out, (float)brows);
}

// Round 8
// 36.866 us; speedup vs baseline: 2.0829x; 2.0829x over previous
//
#include <hip/hip_runtime.h>

#define NC    15
#define NACC  46          // pos_sig[15], all_sig[15], npos[15], ce
#define BLOCK 256
#define WPB   4

typedef float f4 __attribute__((ext_vector_type(4)));
typedef int   i4 __attribute__((ext_vector_type(4)));

template<int CTRL>
__device__ __forceinline__ float dppadd(float x) {
    int y = __builtin_amdgcn_update_dpp(0, __float_as_int(x), CTRL, 0xF, 0xF, true);
    return x + __int_as_float(y);
}
template<int CTRL>
__device__ __forceinline__ int dppi(int x) {
    return __builtin_amdgcn_update_dpp(0, x, CTRL, 0xF, 0xF, true);
}
__device__ __forceinline__ float qsum(float x) {   // sum over quad (one row)
    x = dppadd<0xB1>(x);    // quad_perm xor 1
    x = dppadd<0x4E>(x);    // quad_perm xor 2
    return x;
}
__device__ __forceinline__ int qmin(int x) {       // min over quad
    int a = dppi<0xB1>(x); x = (a < x) ? a : x;
    int b = dppi<0x4E>(x); x = (b < x) ? b : x;
    return x;
}

#define LOADX4(dst, ptr) \
    asm volatile("global_load_dwordx4 %0, %1, off" : "=v"(dst) : "v"(ptr))

__global__ __launch_bounds__(BLOCK, 8) void auch_main(
    const float* __restrict__ logits,
    const int* __restrict__ labels,
    float* __restrict__ ws,
    int niter, int nblk)
{
    __shared__ float s_red[WPB][NACC];

    const int tid  = threadIdx.x;
    const int lane = tid & 63;
    const int wave = tid >> 6;
    const int k    = lane & 3;          // chunk slot within row
    const int rl   = lane >> 2;         // local row 0..15
    const bool k3  = (k == 3);
    const int  cb  = k3 ? 11 : 4 * k;   // first column this lane covers

    const long long gw   = (long long)blockIdx.x * WPB + wave;
    const long long row0 = gw * (16LL * niter) + rl;
    const float* gx = logits + row0 * NC + cb;
    const int*   gl = labels + row0 * NC + cb;

    float accp0=0,accp1=0,accp2=0,accp3=0;     // sigmoid sum over positives
    float acca0=0,acca1=0,acca2=0,acca3=0;     // sigmoid sum over all
    int   np0=0,  np1=0,  np2=0,  np3=0;       // positive counts
    float accce = 0.f;

    auto compute = [&](const f4& x, const i4& l) {
        float e0 = k3 ? 0.f : __expf(x.x);     // k3 slot0 duplicates col 11 -> mask
        float e1 = __expf(x.y);
        float e2 = __expf(x.z);
        float e3 = __expf(x.w);
        float se = qsum(e0 + e1 + e2 + e3);    // row logsumexp denominator

        int lb0 = k3 ? 0 : (l.x & 1);
        int lb1 = l.y & 1, lb2 = l.z & 1, lb3 = l.w & 1;

        float s0 = e0 * __builtin_amdgcn_rcpf(1.f + e0);   // sigmoid = e/(1+e); masked -> 0
        float s1 = e1 * __builtin_amdgcn_rcpf(1.f + e1);
        float s2 = e2 * __builtin_amdgcn_rcpf(1.f + e2);
        float s3 = e3 * __builtin_amdgcn_rcpf(1.f + e3);
        acca0 += s0; acca1 += s1; acca2 += s2; acca3 += s3;
        accp0 += lb0 ? s0 : 0.f;
        accp1 += lb1 ? s1 : 0.f;
        accp2 += lb2 ? s2 : 0.f;
        accp3 += lb3 ? s3 : 0.f;
        np0 += lb0; np1 += lb1; np2 += lb2; np3 += lb3;

        // first positive column in row (argmax of 0/1 labels)
        int col = lb3 ? cb + 3 : 64;
        col = lb2 ? cb + 2 : col;
        col = lb1 ? cb + 1 : col;
        col = lb0 ? cb     : col;
        float xf = lb3 ? x.w : 0.f;
        xf = lb2 ? x.z : xf;
        xf = lb1 ? x.y : xf;
        xf = lb0 ? x.x : xf;
        int mc = qmin(col);
        float sx = (col == mc) ? xf : 0.f;      // unique owner (col ranges disjoint)
        sx = (mc == 64 && k == 0) ? x.x : sx;   // no positive -> argmax = col 0
        sx = qsum(sx);

        accce += __logf(se) - sx;               // per-quad-uniform; dedup at reduce
    };

    // ---- software-pipelined main loop: 2 x dwordx4 in flight across compute ----
    f4 xA, xB; i4 lA, lB;
    LOADX4(xA, gx); LOADX4(lA, gl);
    for (int i = 0; i < niter; i += 2) {
        LOADX4(xB, gx + 240); LOADX4(lB, gl + 240);
        asm volatile("s_waitcnt vmcnt(2)" ::: "memory");   // xA,lA landed; B in flight
        __builtin_amdgcn_sched_barrier(0);
        compute(xA, lA);
        gx += 480; gl += 480;
        if (i + 2 < niter) {
            LOADX4(xA, gx); LOADX4(lA, gl);
            asm volatile("s_waitcnt vmcnt(2)" ::: "memory");
        } else {
            asm volatile("s_waitcnt vmcnt(0)" ::: "memory");
        }
        __builtin_amdgcn_sched_barrier(0);
        compute(xB, lB);
    }

    // ---- reduce across quads: butterfly over strides 4..32 (k stays fixed) ----
    float npf0 = (float)np0, npf1 = (float)np1, npf2 = (float)np2, npf3 = (float)np3;
#pragma unroll
    for (int m = 4; m <= 32; m <<= 1) {
        accp0 += __shfl_xor(accp0, m); accp1 += __shfl_xor(accp1, m);
        accp2 += __shfl_xor(accp2, m); accp3 += __shfl_xor(accp3, m);
        acca0 += __shfl_xor(acca0, m); acca1 += __shfl_xor(acca1, m);
        acca2 += __shfl_xor(acca2, m); acca3 += __shfl_xor(acca3, m);
        npf0  += __shfl_xor(npf0,  m); npf1  += __shfl_xor(npf1,  m);
        npf2  += __shfl_xor(npf2,  m); npf3  += __shfl_xor(npf3,  m);
        accce += __shfl_xor(accce, m);   // sums one representative lane per quad
    }

    if (lane < 4) {                      // lane == k; classes {4k..} or {12,13,14}
        int base = (lane < 3) ? 4 * lane : 11;
        if (lane < 3) {                  // k3 j0 is the masked duplicate -> skip
            s_red[wave][base] = accp0; s_red[wave][15+base] = acca0; s_red[wave][30+base] = npf0;
        }
        s_red[wave][base+1] = accp1; s_red[wave][15+base+1] = acca1; s_red[wave][30+base+1] = npf1;
        s_red[wave][base+2] = accp2; s_red[wave][15+base+2] = acca2; s_red[wave][30+base+2] = npf2;
        s_red[wave][base+3] = accp3; s_red[wave][15+base+3] = acca3; s_red[wave][30+base+3] = npf3;
    }
    if (lane == 0) s_red[wave][45] = accce;
    __syncthreads();

    // deterministic per-block partials: 46 coalesced-enough stores, no atomics
    if (tid < NACC)
        ws[(size_t)tid * nblk + blockIdx.x] = s_red[0][tid] + s_red[1][tid]
                                            + s_red[2][tid] + s_red[3][tid];
}

// 1 block x 1024 threads: wave w reduces accumulators {w, w+16, w+32};
// per v, 64 lanes stream nblk partials as independent f4 loads (all in flight).
__global__ __launch_bounds__(1024) void auch_finalize(
    const float* __restrict__ ws, float* __restrict__ out, float Bf, int nblk)
{
    __shared__ float s_val[NACC + 2];
    const int tid = threadIdx.x;
    const int wave = tid >> 6, lane = tid & 63;
#pragma unroll
    for (int j = 0; j < 3; ++j) {
        int v = wave + 16 * j;
        if (v < NACC) {
            const f4* p = (const f4*)(ws + (size_t)v * nblk);
            float s = 0.f;
            for (int i = lane; i < nblk / 4; i += 64) {   // 8 rounds at nblk=2048
                f4 t = p[i];
                s += (t.x + t.y) + (t.z + t.w);
            }
#pragma unroll
            for (int off = 32; off > 0; off >>= 1) s += __shfl_xor(s, off);
            if (lane == 0) s_val[v] = s;
        }
    }
    __syncthreads();
    if (tid == 0) {
        float sum_term = 0.f, pen14 = 0.f;
#pragma unroll
        for (int c = 0; c < NC; ++c) {
            float sp = s_val[c];             // sum sigmoid over pos
            float sa = s_val[15 + c];        // sum sigmoid over all
            float np = s_val[30 + c];        // n_pos
            float sn = sa - sp;
            float nn = Bf - np;
            float mp = sp / fmaxf(np, 1.f);
            float mn = sn / fmaxf(nn, 1.f);
            float pen = (np == 0.f) ? (1.f + mn)
                       : ((nn == 0.f) ? (1.f - mp) : (1.f - mp + mn));
            sum_term += pen;
            if (c == NC - 1) pen14 = pen;
        }
        float ce = s_val[45] / Bf;
        out[0] = ce + 0.1f * (sum_term / 15.f);
        out[1] = 0.1f * pen14;
    }
}

extern "C" void kernel_launch(void* const* d_in, const int* in_sizes, int n_in,
                              void* d_out, int out_size, void* d_ws, size_t ws_size,
                              hipStream_t stream)
{
    const float* logits = (const float*)d_in[0];
    const int*   labels = (const int*)d_in[1];
    float* ws  = (float*)d_ws;
    float* out = (float*)d_out;

    const long long total = in_sizes[0];      // B*C = 15728640
    const int brows = (int)(total / NC);      // 1048576

    const int grid  = (ws_size >= (size_t)NACC * 2048 * sizeof(float)) ? 2048 : 1024;
    const int niter = brows / (grid * WPB * 16);   // 8 at grid=2048 (even -> i+=2 ok)

    auch_main<<<grid, BLOCK, 0, stream>>>(logits, labels, ws, niter, grid);
    auch_finalize<<<1, 1024, 0, stream>>>(ws, out, (float)brows, grid);
}